// Round 5
// baseline (456.008 us; speedup 1.0000x reference)
//
#include <hip/hip_runtime.h>
#include <hip/hip_bf16.h>

// EfficientAttention: B=8 N=4096 C=768 H=12 D=64, M = 32768
// prep -> gemm256<QKV,BM256> (q-softmax epilogue; k,v fp16) -> kv_partial
//      -> weff_build -> gemm256<OUT,BM128> (fp32 + bias)
// R5 GEMM: B-operand direct global->reg (weights are L2-resident; -33% LDS reads,
// A-only LDS 64KB), ONE barrier per K-tile (stage t+1 targets the other buffer ->
// no intra-tile region hazards), vmcnt(0) stage-drain hidden under full-tile window.
// T1 XCD swizzle + T2 source-side swizzle on A (0 conflicts, R3-verified) + T5 setprio.

#define AS1 __attribute__((address_space(1)))
#define AS3 __attribute__((address_space(3)))

typedef __attribute__((ext_vector_type(8))) short    s16x8;
typedef __attribute__((ext_vector_type(4))) float    f32x4;
typedef __attribute__((ext_vector_type(8))) _Float16 f16x8;
typedef __attribute__((ext_vector_type(4))) unsigned short u16x4;

__device__ __forceinline__ unsigned short f2bf(float f) {
  union { float f; unsigned u; } v; v.f = f;
  unsigned r = v.u + 0x7FFFu + ((v.u >> 16) & 1u);
  return (unsigned short)(r >> 16);
}

// ---------------- prep: cast x + Wq|Wk|Wv -> bf16, concat bias ----------------
__global__ __launch_bounds__(256) void prep(const float* __restrict__ x,
                                            const float* __restrict__ Wq, const float* __restrict__ Wk,
                                            const float* __restrict__ Wv,
                                            const float* __restrict__ bq, const float* __restrict__ bk,
                                            const float* __restrict__ bv,
                                            unsigned short* __restrict__ x_bf,
                                            unsigned short* __restrict__ wqkv_bf,
                                            float* __restrict__ bqkv) {
  const int XB = 2304;
  if ((int)blockIdx.x >= XB) {
    int j = (blockIdx.x - XB) * 256 + threadIdx.x;
    if (j < 768) bqkv[j] = bq[j];
    else if (j < 1536) bqkv[j] = bk[j - 768];
    else if (j < 2304) bqkv[j] = bv[j - 1536];
    return;
  }
  const int n8x = 3145728, n8w = 73728;
  const int stride = XB * 256;
  for (int i = blockIdx.x * 256 + threadIdx.x; i < n8x + 3 * n8w; i += stride) {
    const float* s; unsigned short* d;
    if (i < n8x) { s = x + (size_t)i * 8; d = x_bf + (size_t)i * 8; }
    else {
      int wi = i - n8x, w = wi / n8w, off = wi - w * n8w;
      const float* ws_ = (w == 0) ? Wq : (w == 1) ? Wk : Wv;
      s = ws_ + (size_t)off * 8; d = wqkv_bf + (size_t)wi * 8;
    }
    f32x4 a = ((const f32x4*)s)[0], b = ((const f32x4*)s)[1];
    u16x4 lo, hi;
    lo[0] = f2bf(a[0]); lo[1] = f2bf(a[1]); lo[2] = f2bf(a[2]); lo[3] = f2bf(a[3]);
    hi[0] = f2bf(b[0]); hi[1] = f2bf(b[1]); hi[2] = f2bf(b[2]); hi[3] = f2bf(b[3]);
    ((u16x4*)d)[0] = lo; ((u16x4*)d)[1] = hi;
  }
}

// ---------------- gemm256: C[M,N] = A[M,K] @ Bm[N,K]^T + bias ----------------
// BM = 128*BMBLK, BN = 256, 8 waves (2 wr x 4 wc). MODE 0: fp32 out. MODE 1: QKV epilogue.
template <int MODE, int BMBLK>
__global__ __launch_bounds__(512, 2) void gemm256(const unsigned short* __restrict__ A,
                                                  const unsigned short* __restrict__ Bm,
                                                  const float* __restrict__ bias,
                                                  void* out0, void* out1, void* out2,
                                                  int N, int K, int nb, int batchedB) {
  constexpr int BM = BMBLK * 128;
  constexpr int MI = BMBLK * 4;
  constexpr int NSTG = 2 * BMBLK;
  __shared__ unsigned short As[2][BM * 64];
  const int tid = threadIdx.x, lane = tid & 63, wid = tid >> 6;
  const int wr = wid >> 2, wc = wid & 3;
  const int cpx = gridDim.x >> 3;
  const int logical = (blockIdx.x & 7) * cpx + (blockIdx.x >> 3);
  const int m0 = (logical / nb) * BM, n0 = (logical % nb) * 256;
  const unsigned short* Bp = Bm + (batchedB ? ((size_t)(m0 >> 12) * 589824) : 0);

  f32x4 acc[MI][4] = {};
  const int srcc8 = ((lane & 7) ^ (lane >> 3)) * 8;   // T2 pre-swizzled source col
  const int r15 = lane & 15, hi8 = (lane >> 4) * 8, sw = (lane & 7) * 8;

  auto stageA = [&](int buf, int k0) {                // NSTG gload_lds / thread
#pragma unroll
    for (int j = 0; j < NSTG; ++j) {
      int row = j * 64 + (tid >> 3);
      __builtin_amdgcn_global_load_lds(
          (const AS1 void*)(A + (size_t)(m0 + row) * K + k0 + srcc8),
          (AS3 void*)(&As[buf][row * 64 + (tid & 7) * 8]), 16, 0, 0);
    }
  };

  const unsigned short* Bw = Bp + (size_t)(n0 + wc * 64 + r15) * K + hi8;
  s16x8 bf[4][2];
  auto loadB = [&](int k0) {                          // 8 x dwordx4 global->reg (L2-hot)
#pragma unroll
    for (int j = 0; j < 4; ++j)
#pragma unroll
      for (int kk = 0; kk < 2; ++kk)
        bf[j][kk] = *(const s16x8*)(Bw + (size_t)j * 16 * K + k0 + kk * 32);
  };

  s16x8 af[4][2];
  auto readA = [&](int buf, int grp) {                // 8 x ds_read_b128
    const unsigned short* base = &As[buf][(wr * (BM / 2) + grp * 64) * 64];
#pragma unroll
    for (int i = 0; i < 4; ++i)
#pragma unroll
      for (int kk = 0; kk < 2; ++kk)
        af[i][kk] = *(const s16x8*)(base + (i * 16 + r15) * 64 + ((kk * 32 + hi8) ^ sw));
  };
  auto mfma32 = [&](int mi0) {
    __builtin_amdgcn_s_setprio(1);
#pragma unroll
    for (int i = 0; i < 4; ++i)
#pragma unroll
      for (int j = 0; j < 4; ++j)
#pragma unroll
        for (int kk = 0; kk < 2; ++kk)
          acc[mi0 + i][j] = __builtin_amdgcn_mfma_f32_16x16x32_bf16(
              af[i][kk], bf[j][kk], acc[mi0 + i][j], 0, 0, 0);
    __builtin_amdgcn_s_setprio(0);
  };

  const int nt = K >> 6;
  stageA(0, 0);
  asm volatile("s_waitcnt vmcnt(0)" ::: "memory");
  __builtin_amdgcn_s_barrier();

  for (int t = 0; t < nt; ++t) {
    const int buf = t & 1;
    loadB(t << 6);                                    // needed soonest; issue first
    if (t + 1 < nt) stageA(buf ^ 1, (t + 1) << 6);    // other buffer: no region hazard
    readA(buf, 0);
    mfma32(0);
    if constexpr (BMBLK == 2) {
      readA(buf, 1);
      mfma32(4);
    }
    asm volatile("s_waitcnt vmcnt(0)" ::: "memory");  // stage(t+1) had ~full tile to land
    __builtin_amdgcn_s_barrier();
  }

  // ---------------- epilogue ----------------
  const int g = lane >> 4, c15 = lane & 15;
  float bj[4];
#pragma unroll
  for (int j = 0; j < 4; ++j) bj[j] = bias[n0 + wc * 64 + j * 16 + c15];

  if (MODE == 0) {
    float* out = (float*)out0;
#pragma unroll
    for (int mi = 0; mi < MI; ++mi)
#pragma unroll
      for (int j = 0; j < 4; ++j) {
        int gr = m0 + wr * (BM / 2) + mi * 16 + g * 4;
        int gc = n0 + wc * 64 + j * 16 + c15;
#pragma unroll
        for (int r = 0; r < 4; ++r)
          out[(size_t)(gr + r) * N + gc] = acc[mi][j][r] + bj[j];
      }
  } else {
    if (n0 < 768) {            // q block: per-row softmax over this wave's 64 cols (one head)
      unsigned short* qsm = (unsigned short*)out0;
      const int cbase = n0 + wc * 64;
#pragma unroll
      for (int mi = 0; mi < MI; ++mi) {
#pragma unroll
        for (int r = 0; r < 4; ++r) {
          int gr = m0 + wr * (BM / 2) + mi * 16 + g * 4 + r;
          float v[4];
#pragma unroll
          for (int j = 0; j < 4; ++j) v[j] = acc[mi][j][r] + bj[j];
          float mx = fmaxf(fmaxf(v[0], v[1]), fmaxf(v[2], v[3]));
#pragma unroll
          for (int st = 1; st < 16; st <<= 1) mx = fmaxf(mx, __shfl_xor(mx, st));
          float p[4], sm = 0.f;
#pragma unroll
          for (int j = 0; j < 4; ++j) { p[j] = __expf(v[j] - mx); sm += p[j]; }
#pragma unroll
          for (int st = 1; st < 16; st <<= 1) sm += __shfl_xor(sm, st);
          float inv = 1.0f / sm;
#pragma unroll
          for (int j = 0; j < 4; ++j)
            qsm[(size_t)gr * 768 + cbase + j * 16 + c15] = f2bf(p[j] * inv);
        }
      }
    } else {                   // k or v block: fp16 compact store
      _Float16* dst = (n0 < 1536) ? (_Float16*)out1 : (_Float16*)out2;
      const int cbase = (n0 < 1536 ? n0 - 768 : n0 - 1536) + wc * 64;
#pragma unroll
      for (int mi = 0; mi < MI; ++mi)
#pragma unroll
        for (int j = 0; j < 4; ++j) {
          int gr = m0 + wr * (BM / 2) + mi * 16 + g * 4;
          int cc = cbase + j * 16 + c15;
#pragma unroll
          for (int r = 0; r < 4; ++r)
            dst[(size_t)(gr + r) * 768 + cc] = (_Float16)(acc[mi][j][r] + bj[j]);
        }
    }
  }
}

// ---------------- KV partial: kv_raw[bh,d,e] += sum_n exp(k[n,d]) v[n,e]; z += sum exp(k) ----------------
__global__ __launch_bounds__(256) void kv_partial(const _Float16* __restrict__ kh,
                                                  const _Float16* __restrict__ vh,
                                                  float* __restrict__ kv_raw,
                                                  float* __restrict__ z_raw) {
  const int bh = blockIdx.x, b = bh / 12, h = bh % 12;
  const int split = blockIdx.y;
  __shared__ float ek_s[64][68];
  __shared__ float v_s[64][68];
  const int t = threadIdx.x;
  const int d0 = (t >> 4) * 4, e0 = (t & 15) * 4;
  const int zd = t & 63, zq = t >> 6;
  float acc[4][4] = {};
  float zp = 0.f;
  const size_t base = (size_t)b * 4096 * 768 + h * 64;

  for (int nc = 0; nc < 8; ++nc) {
    int n0 = split * 512 + nc * 64;
#pragma unroll
    for (int j = 0; j < 2; ++j) {
      int vi = t + j * 256;
      int row = vi >> 3, c8 = (vi & 7) * 8;
      size_t gp = base + (size_t)(n0 + row) * 768 + c8;
      f16x8 k8 = *(const f16x8*)(kh + gp);
      f16x8 v8 = *(const f16x8*)(vh + gp);
      f32x4 e0v, e1v, v0v, v1v;
#pragma unroll
      for (int u = 0; u < 4; ++u) {
        e0v[u] = __expf((float)k8[u]); e1v[u] = __expf((float)k8[4 + u]);
        v0v[u] = (float)v8[u];         v1v[u] = (float)v8[4 + u];
      }
      *(f32x4*)&ek_s[row][c8] = e0v; *(f32x4*)&ek_s[row][c8 + 4] = e1v;
      *(f32x4*)&v_s[row][c8]  = v0v; *(f32x4*)&v_s[row][c8 + 4]  = v1v;
    }
    __syncthreads();
#pragma unroll 4
    for (int r = 0; r < 16; ++r) zp += ek_s[zq * 16 + r][zd];
#pragma unroll 8
    for (int n = 0; n < 64; ++n) {
      f32x4 ekv = *(const f32x4*)&ek_s[n][d0];
      f32x4 vv  = *(const f32x4*)&v_s[n][e0];
#pragma unroll
      for (int i = 0; i < 4; ++i)
#pragma unroll
        for (int j = 0; j < 4; ++j)
          acc[i][j] += ekv[i] * vv[j];
    }
    __syncthreads();
  }
  float* kvp = kv_raw + (size_t)bh * 4096;
#pragma unroll
  for (int i = 0; i < 4; ++i)
#pragma unroll
    for (int j = 0; j < 4; ++j)
      atomicAdd(&kvp[(d0 + i) * 64 + e0 + j], acc[i][j]);
  atomicAdd(&z_raw[bh * 64 + zd], zp);
}

// ---------------- Weff: weffT[b][c][h*64+d] = sum_e kv_n[b,h,d,e] * Wp[c][h*64+e] ----------------
__global__ __launch_bounds__(256) void weff_build(const float* __restrict__ kv_raw,
                                                  const float* __restrict__ z_raw,
                                                  const float* __restrict__ Wp,
                                                  unsigned short* __restrict__ weffT) {
  const int c0 = blockIdx.x * 64, h = blockIdx.y, b = blockIdx.z;
  const int bh = b * 12 + h;
  __shared__ float kvn[64][65];
  const int t = threadIdx.x;
#pragma unroll
  for (int i = 0; i < 16; ++i) {
    int idx = t + i * 256;
    int d = idx >> 6;
    kvn[d][idx & 63] = kv_raw[(size_t)bh * 4096 + idx] / (z_raw[bh * 64 + d] * 8.0f);
  }
  __syncthreads();
  const int c = c0 + (t >> 2);
  const int d0 = (t & 3) * 16;
  const float* wrow = Wp + (size_t)c * 768 + h * 64;
  float acc[16] = {};
#pragma unroll 8
  for (int e = 0; e < 64; ++e) {
    float w = wrow[e];
#pragma unroll
    for (int dd = 0; dd < 16; ++dd) acc[dd] += w * kvn[d0 + dd][e];
  }
  unsigned short* orow = weffT + (size_t)b * 589824 + (size_t)c * 768 + h * 64 + d0;
#pragma unroll
  for (int dd = 0; dd < 16; ++dd) orow[dd] = f2bf(acc[dd]);
}

// ---------------- launch ----------------
extern "C" void kernel_launch(void* const* d_in, const int* in_sizes, int n_in,
                              void* d_out, int out_size, void* d_ws, size_t ws_size,
                              hipStream_t stream) {
  const float* x  = (const float*)d_in[0];
  const float* Wq = (const float*)d_in[1];
  const float* bq = (const float*)d_in[2];
  const float* Wk = (const float*)d_in[3];
  const float* bk = (const float*)d_in[4];
  const float* Wv = (const float*)d_in[5];
  const float* bv = (const float*)d_in[6];
  const float* Wp = (const float*)d_in[7];
  const float* bp = (const float*)d_in[8];

  const size_t MT = 32768;
  const size_t XE = MT * 768;
  const size_t WE = 768 * 768;

  unsigned short* x_bf    = (unsigned short*)d_ws;           // 48 MB
  unsigned short* wqkv_bf = x_bf + XE;                        // 3.4 MB
  unsigned short* q_sm    = wqkv_bf + 3 * WE;                 // 48 MB (bf16 softmaxed q)
  _Float16* k_h = (_Float16*)(q_sm + XE);                     // 48 MB
  _Float16* v_h = k_h + XE;                                   // 48 MB
  unsigned short* weffT = (unsigned short*)(v_h + XE);        // 9.4 MB
  float* bqkv   = (float*)(weffT + 8 * WE);
  float* kv_raw = bqkv + 2304;
  float* z_raw  = kv_raw + 96 * 4096;

  prep<<<2313, 256, 0, stream>>>(x, Wq, Wk, Wv, bq, bk, bv, x_bf, wqkv_bf, bqkv);
  hipMemsetAsync(kv_raw, 0, (96 * 4096 + 96 * 64) * sizeof(float), stream);

  // fused QKV GEMM: [32768,768] x [2304,768]^T ; epilogue q-softmax / k,v fp16
  gemm256<1, 2><<<1152, 512, 0, stream>>>(x_bf, wqkv_bf, bqkv, q_sm, k_h, v_h, 2304, 768, 9, 0);

  kv_partial<<<dim3(96, 8), 256, 0, stream>>>(k_h, v_h, kv_raw, z_raw);
  weff_build<<<dim3(12, 12, 8), 256, 0, stream>>>(kv_raw, z_raw, Wp, weffT);

  // out = q_sm @ Weff_b^T + bp  (BM=128)
  gemm256<0, 1><<<768, 512, 0, stream>>>(q_sm, weffT, bp, d_out, nullptr, nullptr, 768, 768, 3, 1);
}

// Round 6
// 381.492 us; speedup vs baseline: 1.1953x; 1.1953x over previous
//
#include <hip/hip_runtime.h>
#include <hip/hip_bf16.h>

// EfficientAttention: B=8 N=4096 C=768 H=12 D=64, M = 32768
// prep (cast + bias + zero-kv) -> gemm256<QKV,BM256> (q-softmax epilogue; k,v fp16)
//   -> kv_partial -> weff_build -> gemm256<OUT,BM128> (fp32 + bias)
// R6: R4's verified 4-phase dbuf ledger restored; MFMA switched to 32x32x16
// (faster pipe, half the instruction count); BMBLK=1 read-then-stage hazard fixed;
// memset folded into prep. T1 XCD swizzle, T2 source-side swizzle (0 conflicts), T5 setprio.

#define AS1 __attribute__((address_space(1)))
#define AS3 __attribute__((address_space(3)))

typedef __attribute__((ext_vector_type(8))) short    s16x8;
typedef __attribute__((ext_vector_type(4))) float    f32x4;
typedef __attribute__((ext_vector_type(16))) float   f32x16;
typedef __attribute__((ext_vector_type(8))) _Float16 f16x8;
typedef __attribute__((ext_vector_type(4))) _Float16 f16x4;
typedef __attribute__((ext_vector_type(4))) unsigned short u16x4;

__device__ __forceinline__ unsigned short f2bf(float f) {
  union { float f; unsigned u; } v; v.f = f;
  unsigned r = v.u + 0x7FFFu + ((v.u >> 16) & 1u);
  return (unsigned short)(r >> 16);
}

// ---------------- prep: cast x + Wq|Wk|Wv -> bf16, concat bias, zero kv accum ----------------
__global__ __launch_bounds__(256) void prep(const float* __restrict__ x,
                                            const float* __restrict__ Wq, const float* __restrict__ Wk,
                                            const float* __restrict__ Wv,
                                            const float* __restrict__ bq, const float* __restrict__ bk,
                                            const float* __restrict__ bv,
                                            unsigned short* __restrict__ x_bf,
                                            unsigned short* __restrict__ wqkv_bf,
                                            float* __restrict__ bqkv,
                                            float* __restrict__ kvz) {
  const int XB = 2304;
  if ((int)blockIdx.x >= XB) {                    // 9 tail blocks: bias concat + kv zero
    int j = (blockIdx.x - XB) * 256 + threadIdx.x;
    if (j < 768) bqkv[j] = bq[j];
    else if (j < 1536) bqkv[j] = bk[j - 768];
    else if (j < 2304) bqkv[j] = bv[j - 1536];
    const int NZ = 96 * 4096 + 96 * 64;
    for (int i = (blockIdx.x - XB) * 256 + threadIdx.x; i < NZ; i += 9 * 256) kvz[i] = 0.f;
    return;
  }
  const int n8x = 3145728, n8w = 73728;
  const int stride = XB * 256;
  for (int i = blockIdx.x * 256 + threadIdx.x; i < n8x + 3 * n8w; i += stride) {
    const float* s; unsigned short* d;
    if (i < n8x) { s = x + (size_t)i * 8; d = x_bf + (size_t)i * 8; }
    else {
      int wi = i - n8x, w = wi / n8w, off = wi - w * n8w;
      const float* ws_ = (w == 0) ? Wq : (w == 1) ? Wk : Wv;
      s = ws_ + (size_t)off * 8; d = wqkv_bf + (size_t)wi * 8;
    }
    f32x4 a = ((const f32x4*)s)[0], b = ((const f32x4*)s)[1];
    u16x4 lo, hi;
    lo[0] = f2bf(a[0]); lo[1] = f2bf(a[1]); lo[2] = f2bf(a[2]); lo[3] = f2bf(a[3]);
    hi[0] = f2bf(b[0]); hi[1] = f2bf(b[1]); hi[2] = f2bf(b[2]); hi[3] = f2bf(b[3]);
    ((u16x4*)d)[0] = lo; ((u16x4*)d)[1] = hi;
  }
}

// ---------------- gemm256: C[M,N] = A[M,K] @ Bm[N,K]^T + bias ----------------
// BM = 128*BMBLK, BN = 256, 8 waves (2 wr x 4 wc), wave tile BM/2 x 64.
// 32x32x16 MFMA: A/B frag row|col = lane&31, k = (lane>>5)*8+j ;
// C/D: col = lane&31, row = (reg&3) + 8*(reg>>2) + 4*(lane>>5)  [m74/m101].
template <int MODE, int BMBLK>
__global__ __launch_bounds__(512, 2) void gemm256(const unsigned short* __restrict__ A,
                                                  const unsigned short* __restrict__ Bm,
                                                  const float* __restrict__ bias,
                                                  void* out0, void* out1, void* out2,
                                                  int N, int K, int nb, int batchedB) {
  constexpr int BM  = BMBLK * 128;
  constexpr int MIH = BMBLK;            // 32-row frags per half
  constexpr int MIF = BMBLK * 2;        // 32-row frags per wave
  __shared__ unsigned short As[2][BM * 64];
  __shared__ unsigned short Bs[2][256 * 64];
  const int tid = threadIdx.x, lane = tid & 63, wid = tid >> 6;
  const int wr = wid >> 2, wc = wid & 3;
  const int cpx = gridDim.x >> 3;
  const int logical = (blockIdx.x & 7) * cpx + (blockIdx.x >> 3);
  const int m0 = (logical / nb) * BM, n0 = (logical % nb) * 256;
  const unsigned short* Bp = Bm + (batchedB ? ((size_t)(m0 >> 12) * 589824) : 0);

  f32x16 acc[MIF][2] = {};
  const int srcc8 = ((lane & 7) ^ (lane >> 3)) * 8;   // T2 pre-swizzled source col
  const int l31 = lane & 31, g8 = (lane >> 5) * 8, sw = (lane & 7) * 8;

  auto stageA = [&](int buf, int which, int k0) {     // 2 gload_lds / thread
    if constexpr (BMBLK == 2) {
#pragma unroll
      for (int half = 0; half < 2; ++half) {
        int row = half * 128 + which * 64 + (tid >> 3);
        __builtin_amdgcn_global_load_lds(
            (const AS1 void*)(A + (size_t)(m0 + row) * K + k0 + srcc8),
            (AS3 void*)(&As[buf][row * 64 + (tid & 7) * 8]), 16, 0, 0);
      }
    } else {
#pragma unroll
      for (int j = 0; j < 2; ++j) {
        int row = j * 64 + (tid >> 3);
        __builtin_amdgcn_global_load_lds(
            (const AS1 void*)(A + (size_t)(m0 + row) * K + k0 + srcc8),
            (AS3 void*)(&As[buf][row * 64 + (tid & 7) * 8]), 16, 0, 0);
      }
    }
  };
  auto stageB = [&](int buf, int which, int k0) {     // 2 gload_lds / thread
#pragma unroll
    for (int j = 0; j < 2; ++j) {
      int idx = tid + j * 512;
      int half = idx >> 9, sub = (idx >> 8) & 1;
      int row = half * 128 + sub * 64 + which * 32 + ((idx & 255) >> 3);
      __builtin_amdgcn_global_load_lds(
          (const AS1 void*)(Bp + (size_t)(n0 + row) * K + k0 + srcc8),
          (AS3 void*)(&Bs[buf][row * 64 + (idx & 7) * 8]), 16, 0, 0);
    }
  };

  s16x8 af[2][4], bf[2][4];
  auto readA = [&](int buf, int h) {    // MIH*4 x ds_read_b128
    const unsigned short* base = &As[buf][(wr * (BM / 2) + h * (BM / 4)) * 64];
#pragma unroll
    for (int i = 0; i < MIH; ++i)
#pragma unroll
      for (int ks = 0; ks < 4; ++ks)
        af[BMBLK == 2 ? i : h][ks] =
            *(const s16x8*)(base + (i * 32 + l31) * 64 + ((ks * 16 + g8) ^ sw));
  };
  auto readB = [&](int buf, int q) {    // 4 x ds_read_b128
    const unsigned short* base = &Bs[buf][(wc >> 1) * 128 * 64];
    int lrow = (wc & 1) * 64 + q * 32 + l31;
#pragma unroll
    for (int ks = 0; ks < 4; ++ks)
      bf[q][ks] = *(const s16x8*)(base + lrow * 64 + ((ks * 16 + g8) ^ sw));
  };
  auto mfmaQ = [&](int h, int q) {      // MIH*4 MFMA, one quadrant x K=64
    __builtin_amdgcn_s_setprio(1);
#pragma unroll
    for (int ks = 0; ks < 4; ++ks)
#pragma unroll
      for (int i = 0; i < MIH; ++i)
        acc[h * MIH + i][q] = __builtin_amdgcn_mfma_f32_32x32x16_bf16(
            af[BMBLK == 2 ? i : h][ks], bf[q][ks], acc[h * MIH + i][q], 0, 0, 0);
    __builtin_amdgcn_s_setprio(0);
  };

  const int nt = K >> 6;
  // prologue: stage tiles 0,1
  if constexpr (BMBLK == 2) {
    stageA(0, 0, 0);  stageA(0, 1, 0);  stageB(0, 0, 0);  stageB(0, 1, 0);
    stageA(1, 0, 64); stageA(1, 1, 64); stageB(1, 0, 64); stageB(1, 1, 64);
    asm volatile("s_waitcnt vmcnt(8)" ::: "memory");
  } else {
    stageA(0, 0, 0);  stageB(0, 0, 0);  stageB(0, 1, 0);
    stageA(1, 0, 64); stageB(1, 0, 64); stageB(1, 1, 64);
    asm volatile("s_waitcnt vmcnt(6)" ::: "memory");
  }
  __builtin_amdgcn_s_barrier();

  for (int s = 0; s < nt; ++s) {
    const int buf = s & 1;
    const int k2 = (s + 2) << 6;
    const bool pf = (s + 2) < nt;
    if constexpr (BMBLK == 2) {
      // P1: read A_lo + B_lo ; MFMA (h0,q0)
      readA(buf, 0); readB(buf, 0);
      asm volatile("" ::: "memory");
      __builtin_amdgcn_s_barrier();
      asm volatile("s_waitcnt lgkmcnt(0)" ::: "memory");
      mfmaQ(0, 0);
      asm volatile("" ::: "memory");
      __builtin_amdgcn_s_barrier();
      // P2: read B_hi ; stage A0,B0(s+2) ; MFMA (h0,q1)
      readB(buf, 1);
      if (pf) { stageA(buf, 0, k2); stageB(buf, 0, k2); }
      asm volatile("" ::: "memory");
      __builtin_amdgcn_s_barrier();
      asm volatile("s_waitcnt lgkmcnt(0)" ::: "memory");
      mfmaQ(0, 1);
      asm volatile("" ::: "memory");
      __builtin_amdgcn_s_barrier();
      // P3: read A_hi ; stage B1(s+2) ; MFMA (h1,q1)
      readA(buf, 1);
      if (pf) stageB(buf, 1, k2);
      asm volatile("" ::: "memory");
      __builtin_amdgcn_s_barrier();
      asm volatile("s_waitcnt lgkmcnt(0)" ::: "memory");
      mfmaQ(1, 1);
      asm volatile("" ::: "memory");
      __builtin_amdgcn_s_barrier();
      // P4: stage A1(s+2) ; MFMA (h1,q0) ; counted gate
      if (pf) stageA(buf, 1, k2);
      mfmaQ(1, 0);
      if (pf)              asm volatile("s_waitcnt vmcnt(8)" ::: "memory");
      else if (s + 1 < nt) asm volatile("s_waitcnt vmcnt(0)" ::: "memory");
      __builtin_amdgcn_s_barrier();
    } else {
      // P1: ALL reads ; MFMA (h0,q0)+(h1,q0)   [read-before-stage: no region hazard]
      readA(buf, 0); readA(buf, 1); readB(buf, 0); readB(buf, 1);
      asm volatile("" ::: "memory");
      __builtin_amdgcn_s_barrier();
      asm volatile("s_waitcnt lgkmcnt(0)" ::: "memory");
      mfmaQ(0, 0); mfmaQ(1, 0);
      asm volatile("" ::: "memory");
      __builtin_amdgcn_s_barrier();
      // P2: stage all(s+2) ; MFMA (h0,q1)+(h1,q1) ; counted gate
      if (pf) { stageA(buf, 0, k2); stageB(buf, 0, k2); stageB(buf, 1, k2); }
      mfmaQ(0, 1); mfmaQ(1, 1);
      if (pf)              asm volatile("s_waitcnt vmcnt(6)" ::: "memory");
      else if (s + 1 < nt) asm volatile("s_waitcnt vmcnt(0)" ::: "memory");
      __builtin_amdgcn_s_barrier();
    }
  }

  // ---------------- epilogue (32x32 C layout) ----------------
  const int grp = lane >> 5;
  float bj[2];
#pragma unroll
  for (int q = 0; q < 2; ++q) bj[q] = bias[n0 + wc * 64 + q * 32 + l31];

  if (MODE == 0) {
    float* out = (float*)out0;
#pragma unroll
    for (int mi = 0; mi < MIF; ++mi)
#pragma unroll
      for (int q = 0; q < 2; ++q) {
        int gc = n0 + wc * 64 + q * 32 + l31;
#pragma unroll
        for (int r = 0; r < 16; ++r) {
          int rr = (r & 3) + 8 * (r >> 2) + 4 * grp;
          int gr = m0 + wr * (BM / 2) + mi * 32 + rr;
          out[(size_t)gr * N + gc] = acc[mi][q][r] + bj[q];
        }
      }
  } else {
    if (n0 < 768) {            // q block: per-row softmax over this wave's 64 cols (one head)
      unsigned short* qsm = (unsigned short*)out0;
      const int cbase = n0 + wc * 64;
#pragma unroll
      for (int mi = 0; mi < MIF; ++mi) {
#pragma unroll
        for (int r = 0; r < 16; ++r) {
          int rr = (r & 3) + 8 * (r >> 2) + 4 * grp;
          int gr = m0 + wr * (BM / 2) + mi * 32 + rr;
          float v0 = acc[mi][0][r] + bj[0];
          float v1 = acc[mi][1][r] + bj[1];
          float mx = fmaxf(v0, v1);
#pragma unroll
          for (int st = 1; st < 32; st <<= 1) mx = fmaxf(mx, __shfl_xor(mx, st));
          float p0 = __expf(v0 - mx), p1 = __expf(v1 - mx);
          float sm = p0 + p1;
#pragma unroll
          for (int st = 1; st < 32; st <<= 1) sm += __shfl_xor(sm, st);
          float inv = 1.0f / sm;
          qsm[(size_t)gr * 768 + cbase + l31]      = f2bf(p0 * inv);
          qsm[(size_t)gr * 768 + cbase + 32 + l31] = f2bf(p1 * inv);
        }
      }
    } else {                   // k or v block: fp16 compact store
      _Float16* dst = (n0 < 1536) ? (_Float16*)out1 : (_Float16*)out2;
      const int cbase = (n0 < 1536 ? n0 - 768 : n0 - 1536) + wc * 64;
#pragma unroll
      for (int mi = 0; mi < MIF; ++mi)
#pragma unroll
        for (int q = 0; q < 2; ++q) {
          int cc = cbase + q * 32 + l31;
#pragma unroll
          for (int r = 0; r < 16; ++r) {
            int rr = (r & 3) + 8 * (r >> 2) + 4 * grp;
            int gr = m0 + wr * (BM / 2) + mi * 32 + rr;
            dst[(size_t)gr * 768 + cc] = (_Float16)(acc[mi][q][r] + bj[q]);
          }
        }
    }
  }
}

// ---------------- KV partial: kv_raw[bh,d,e] += sum_n exp(k[n,d]) v[n,e]; z += sum exp(k) ----------------
__global__ __launch_bounds__(256) void kv_partial(const _Float16* __restrict__ kh,
                                                  const _Float16* __restrict__ vh,
                                                  float* __restrict__ kv_raw,
                                                  float* __restrict__ z_raw) {
  const int bh = blockIdx.x, b = bh / 12, h = bh % 12;
  const int split = blockIdx.y;
  __shared__ float ek_s[64][68];
  __shared__ float v_s[64][68];
  const int t = threadIdx.x;
  const int d0 = (t >> 4) * 4, e0 = (t & 15) * 4;
  const int zd = t & 63, zq = t >> 6;
  float acc[4][4] = {};
  float zp = 0.f;
  const size_t base = (size_t)b * 4096 * 768 + h * 64;

  for (int nc = 0; nc < 8; ++nc) {
    int n0 = split * 512 + nc * 64;
#pragma unroll
    for (int j = 0; j < 2; ++j) {
      int vi = t + j * 256;
      int row = vi >> 3, c8 = (vi & 7) * 8;
      size_t gp = base + (size_t)(n0 + row) * 768 + c8;
      f16x8 k8 = *(const f16x8*)(kh + gp);
      f16x8 v8 = *(const f16x8*)(vh + gp);
      f32x4 e0v, e1v, v0v, v1v;
#pragma unroll
      for (int u = 0; u < 4; ++u) {
        e0v[u] = __expf((float)k8[u]); e1v[u] = __expf((float)k8[4 + u]);
        v0v[u] = (float)v8[u];         v1v[u] = (float)v8[4 + u];
      }
      *(f32x4*)&ek_s[row][c8] = e0v; *(f32x4*)&ek_s[row][c8 + 4] = e1v;
      *(f32x4*)&v_s[row][c8]  = v0v; *(f32x4*)&v_s[row][c8 + 4]  = v1v;
    }
    __syncthreads();
#pragma unroll 4
    for (int r = 0; r < 16; ++r) zp += ek_s[zq * 16 + r][zd];
#pragma unroll 8
    for (int n = 0; n < 64; ++n) {
      f32x4 ekv = *(const f32x4*)&ek_s[n][d0];
      f32x4 vv  = *(const f32x4*)&v_s[n][e0];
#pragma unroll
      for (int i = 0; i < 4; ++i)
#pragma unroll
        for (int j = 0; j < 4; ++j)
          acc[i][j] += ekv[i] * vv[j];
    }
    __syncthreads();
  }
  float* kvp = kv_raw + (size_t)bh * 4096;
#pragma unroll
  for (int i = 0; i < 4; ++i)
#pragma unroll
    for (int j = 0; j < 4; ++j)
      atomicAdd(&kvp[(d0 + i) * 64 + e0 + j], acc[i][j]);
  atomicAdd(&z_raw[bh * 64 + zd], zp);
}

// ---------------- Weff: weffT[b][c][h*64+d] = sum_e kv_n[b,h,d,e] * Wp[c][h*64+e] ----------------
__global__ __launch_bounds__(256) void weff_build(const float* __restrict__ kv_raw,
                                                  const float* __restrict__ z_raw,
                                                  const float* __restrict__ Wp,
                                                  unsigned short* __restrict__ weffT) {
  const int c0 = blockIdx.x * 64, h = blockIdx.y, b = blockIdx.z;
  const int bh = b * 12 + h;
  __shared__ float kvn[64][65];
  const int t = threadIdx.x;
#pragma unroll
  for (int i = 0; i < 16; ++i) {
    int idx = t + i * 256;
    int d = idx >> 6;
    kvn[d][idx & 63] = kv_raw[(size_t)bh * 4096 + idx] / (z_raw[bh * 64 + d] * 8.0f);
  }
  __syncthreads();
  const int c = c0 + (t >> 2);
  const int d0 = (t & 3) * 16;
  const float* wrow = Wp + (size_t)c * 768 + h * 64;
  float acc[16] = {};
#pragma unroll 8
  for (int e = 0; e < 64; ++e) {
    float w = wrow[e];
#pragma unroll
    for (int dd = 0; dd < 16; ++dd) acc[dd] += w * kvn[d0 + dd][e];
  }
  unsigned short* orow = weffT + (size_t)b * 589824 + (size_t)c * 768 + h * 64 + d0;
#pragma unroll
  for (int dd = 0; dd < 16; ++dd) orow[dd] = f2bf(acc[dd]);
}

// ---------------- launch ----------------
extern "C" void kernel_launch(void* const* d_in, const int* in_sizes, int n_in,
                              void* d_out, int out_size, void* d_ws, size_t ws_size,
                              hipStream_t stream) {
  const float* x  = (const float*)d_in[0];
  const float* Wq = (const float*)d_in[1];
  const float* bq = (const float*)d_in[2];
  const float* Wk = (const float*)d_in[3];
  const float* bk = (const float*)d_in[4];
  const float* Wv = (const float*)d_in[5];
  const float* bv = (const float*)d_in[6];
  const float* Wp = (const float*)d_in[7];
  const float* bp = (const float*)d_in[8];

  const size_t MT = 32768;
  const size_t XE = MT * 768;
  const size_t WE = 768 * 768;

  unsigned short* x_bf    = (unsigned short*)d_ws;           // 48 MB
  unsigned short* wqkv_bf = x_bf + XE;                        // 3.4 MB
  unsigned short* q_sm    = wqkv_bf + 3 * WE;                 // 48 MB (bf16 softmaxed q)
  _Float16* k_h = (_Float16*)(q_sm + XE);                     // 48 MB
  _Float16* v_h = k_h + XE;                                   // 48 MB
  unsigned short* weffT = (unsigned short*)(v_h + XE);        // 9.4 MB
  float* bqkv   = (float*)(weffT + 8 * WE);
  float* kv_raw = bqkv + 2304;
  float* z_raw  = kv_raw + 96 * 4096;

  prep<<<2313, 256, 0, stream>>>(x, Wq, Wk, Wv, bq, bk, bv, x_bf, wqkv_bf, bqkv, kv_raw);

  // fused QKV GEMM: [32768,768] x [2304,768]^T ; epilogue q-softmax / k,v fp16
  gemm256<1, 2><<<1152, 512, 0, stream>>>(x_bf, wqkv_bf, bqkv, q_sm, k_h, v_h, 2304, 768, 9, 0);

  kv_partial<<<dim3(96, 8), 256, 0, stream>>>(k_h, v_h, kv_raw, z_raw);
  weff_build<<<dim3(12, 12, 8), 256, 0, stream>>>(kv_raw, z_raw, Wp, weffT);

  // out = q_sm @ Weff_b^T + bp  (BM=128: 768 blocks = 3 exact rounds)
  gemm256<0, 1><<<768, 512, 0, stream>>>(q_sm, weffT, bp, d_out, nullptr, nullptr, 768, 768, 3, 1);
}

// Round 7
// 339.283 us; speedup vs baseline: 1.3440x; 1.1244x over previous
//
#include <hip/hip_runtime.h>
#include <hip/hip_bf16.h>

// EfficientAttention: B=8 N=4096 C=768 H=12 D=64, M = 32768
// prep (cast + bias) -> gemm256<QKV,BM256> (q-softmax epilogue; k,v fp16)
//   -> kv_partial (PRIVATE split buffers, no atomics) -> weff_build (sums partials)
//   -> gemm256<OUT,BM128> (fp32 + bias)
// R7: exact R4 GEMM restored (16x16x32, 4-phase dbuf, counted vmcnt, T1/T2/T5;
// 163us / 0 conflicts verified) + lgkmcnt(8) pre-drain in P1 (m201 template);
// kv_partial atomics eliminated (G12): per-split private accum + LDS z-reduce.

#define AS1 __attribute__((address_space(1)))
#define AS3 __attribute__((address_space(3)))

typedef __attribute__((ext_vector_type(8))) short    s16x8;
typedef __attribute__((ext_vector_type(4))) float    f32x4;
typedef __attribute__((ext_vector_type(8))) _Float16 f16x8;
typedef __attribute__((ext_vector_type(4))) unsigned short u16x4;

__device__ __forceinline__ unsigned short f2bf(float f) {
  union { float f; unsigned u; } v; v.f = f;
  unsigned r = v.u + 0x7FFFu + ((v.u >> 16) & 1u);
  return (unsigned short)(r >> 16);
}

// ---------------- prep: cast x + Wq|Wk|Wv -> bf16, concat bias ----------------
__global__ __launch_bounds__(256) void prep(const float* __restrict__ x,
                                            const float* __restrict__ Wq, const float* __restrict__ Wk,
                                            const float* __restrict__ Wv,
                                            const float* __restrict__ bq, const float* __restrict__ bk,
                                            const float* __restrict__ bv,
                                            unsigned short* __restrict__ x_bf,
                                            unsigned short* __restrict__ wqkv_bf,
                                            float* __restrict__ bqkv) {
  const int XB = 2304;
  if ((int)blockIdx.x >= XB) {                    // 9 tail blocks: bias concat
    int j = (blockIdx.x - XB) * 256 + threadIdx.x;
    if (j < 768) bqkv[j] = bq[j];
    else if (j < 1536) bqkv[j] = bk[j - 768];
    else if (j < 2304) bqkv[j] = bv[j - 1536];
    return;
  }
  const int n8x = 3145728, n8w = 73728;
  const int stride = XB * 256;
  for (int i = blockIdx.x * 256 + threadIdx.x; i < n8x + 3 * n8w; i += stride) {
    const float* s; unsigned short* d;
    if (i < n8x) { s = x + (size_t)i * 8; d = x_bf + (size_t)i * 8; }
    else {
      int wi = i - n8x, w = wi / n8w, off = wi - w * n8w;
      const float* ws_ = (w == 0) ? Wq : (w == 1) ? Wk : Wv;
      s = ws_ + (size_t)off * 8; d = wqkv_bf + (size_t)wi * 8;
    }
    f32x4 a = ((const f32x4*)s)[0], b = ((const f32x4*)s)[1];
    u16x4 lo, hi;
    lo[0] = f2bf(a[0]); lo[1] = f2bf(a[1]); lo[2] = f2bf(a[2]); lo[3] = f2bf(a[3]);
    hi[0] = f2bf(b[0]); hi[1] = f2bf(b[1]); hi[2] = f2bf(b[2]); hi[3] = f2bf(b[3]);
    ((u16x4*)d)[0] = lo; ((u16x4*)d)[1] = hi;
  }
}

// ---------------- gemm256: C[M,N] = A[M,K] @ Bm[N,K]^T + bias (R4-verified) ----------------
template <int MODE, int BMBLK>
__global__ __launch_bounds__(512, 2) void gemm256(const unsigned short* __restrict__ A,
                                                  const unsigned short* __restrict__ Bm,
                                                  const float* __restrict__ bias,
                                                  void* out0, void* out1, void* out2,
                                                  int N, int K, int nb, int batchedB) {
  constexpr int BM = BMBLK * 128;
  constexpr int MI = BMBLK * 4;
  __shared__ unsigned short As[2][BM * 64];
  __shared__ unsigned short Bs[2][256 * 64];
  const int tid = threadIdx.x, lane = tid & 63, wid = tid >> 6;
  const int wr = wid >> 2, wc = wid & 3;
  const int cpx = gridDim.x >> 3;
  const int logical = (blockIdx.x & 7) * cpx + (blockIdx.x >> 3);
  const int m0 = (logical / nb) * BM, n0 = (logical % nb) * 256;
  const unsigned short* Bp = Bm + (batchedB ? ((size_t)(m0 >> 12) * 589824) : 0);

  f32x4 acc[MI][4] = {};
  const int srcc8 = ((lane & 7) ^ (lane >> 3)) * 8;   // T2 pre-swizzled source col
  const int r15 = lane & 15, hi8 = (lane >> 4) * 8, sw = (lane & 7) * 8;

  auto stageA = [&](int buf, int which, int k0) {     // 2 gload_lds / thread
    if constexpr (BMBLK == 2) {
#pragma unroll
      for (int half = 0; half < 2; ++half) {
        int row = half * 128 + which * 64 + (tid >> 3);
        __builtin_amdgcn_global_load_lds(
            (const AS1 void*)(A + (size_t)(m0 + row) * K + k0 + srcc8),
            (AS3 void*)(&As[buf][row * 64 + (tid & 7) * 8]), 16, 0, 0);
      }
    } else {
#pragma unroll
      for (int j = 0; j < 2; ++j) {
        int row = j * 64 + (tid >> 3);
        __builtin_amdgcn_global_load_lds(
            (const AS1 void*)(A + (size_t)(m0 + row) * K + k0 + srcc8),
            (AS3 void*)(&As[buf][row * 64 + (tid & 7) * 8]), 16, 0, 0);
      }
    }
  };
  auto stageB = [&](int buf, int which, int k0) {     // 2 gload_lds / thread
#pragma unroll
    for (int j = 0; j < 2; ++j) {
      int idx = tid + j * 512;
      int half = idx >> 9, sub = (idx >> 8) & 1;
      int row = half * 128 + sub * 64 + which * 32 + ((idx & 255) >> 3);
      __builtin_amdgcn_global_load_lds(
          (const AS1 void*)(Bp + (size_t)(n0 + row) * K + k0 + srcc8),
          (AS3 void*)(&Bs[buf][row * 64 + (idx & 7) * 8]), 16, 0, 0);
    }
  };

  s16x8 af[4][2], bf[4][2];
  auto readA = [&](int buf, int grp) {                // 8 x ds_read_b128
    const unsigned short* base = &As[buf][(wr * (BM / 2) + grp * 64) * 64];
#pragma unroll
    for (int i = 0; i < 4; ++i)
#pragma unroll
      for (int kk = 0; kk < 2; ++kk)
        af[i][kk] = *(const s16x8*)(base + (i * 16 + r15) * 64 + ((kk * 32 + hi8) ^ sw));
  };
  auto readB = [&](int buf, int grp) {                // 4 x ds_read_b128
    const unsigned short* base = &Bs[buf][(wc >> 1) * 128 * 64];
#pragma unroll
    for (int jj = 0; jj < 2; ++jj) {
      int j = grp * 2 + jj;
      int lrow = (wc & 1) * 64 + j * 16 + r15;
#pragma unroll
      for (int kk = 0; kk < 2; ++kk)
        bf[j][kk] = *(const s16x8*)(base + lrow * 64 + ((kk * 32 + hi8) ^ sw));
    }
  };

  // kk OUTER: consecutive MFMAs hit distinct acc regs
#define MFMA16(MI0, J0)                                                             \
  __builtin_amdgcn_s_setprio(1);                                                    \
  _Pragma("unroll") for (int kk = 0; kk < 2; ++kk)                                  \
  _Pragma("unroll") for (int i = 0; i < 4; ++i)                                     \
  _Pragma("unroll") for (int jj = 0; jj < 2; ++jj)                                  \
    acc[(MI0) + i][(J0) + jj] = __builtin_amdgcn_mfma_f32_16x16x32_bf16(            \
        af[i][kk], bf[(J0) + jj][kk], acc[(MI0) + i][(J0) + jj], 0, 0, 0);          \
  __builtin_amdgcn_s_setprio(0);

  const int nt = K >> 6;
  // prologue: stage tiles 0,1
  if constexpr (BMBLK == 2) {
    stageA(0, 0, 0);  stageA(0, 1, 0);  stageB(0, 0, 0);  stageB(0, 1, 0);
    stageA(1, 0, 64); stageA(1, 1, 64); stageB(1, 0, 64); stageB(1, 1, 64);
    asm volatile("s_waitcnt vmcnt(8)" ::: "memory");
  } else {
    stageA(0, 0, 0);  stageB(0, 0, 0);  stageB(0, 1, 0);
    stageA(1, 0, 64); stageB(1, 0, 64); stageB(1, 1, 64);
    asm volatile("s_waitcnt vmcnt(6)" ::: "memory");
  }
  __builtin_amdgcn_s_barrier();

  for (int s = 0; s < nt; ++s) {
    const int buf = s & 1;
    const int k2 = (s + 2) << 6;
    const bool pf = (s + 2) < nt;
    if constexpr (BMBLK == 2) {
      // P1: read A_lo + B_lo (12 ds_reads) ; pre-drain lgkm(8) ; MFMA (mi0-3, j0-1)
      readA(buf, 0); readB(buf, 0);
      asm volatile("s_waitcnt lgkmcnt(8)" ::: "memory");
      __builtin_amdgcn_s_barrier();
      asm volatile("s_waitcnt lgkmcnt(0)" ::: "memory");
      MFMA16(0, 0)
      asm volatile("" ::: "memory");
      __builtin_amdgcn_s_barrier();
      // P2: read B_hi ; stage A0,B0(s+2) ; MFMA (mi0-3, j2-3)
      readB(buf, 1);
      if (pf) { stageA(buf, 0, k2); stageB(buf, 0, k2); }
      asm volatile("" ::: "memory");
      __builtin_amdgcn_s_barrier();
      asm volatile("s_waitcnt lgkmcnt(0)" ::: "memory");
      MFMA16(0, 2)
      asm volatile("" ::: "memory");
      __builtin_amdgcn_s_barrier();
      // P3: read A_hi ; stage B1(s+2) ; MFMA (mi4-7, j2-3)
      readA(buf, 1);
      if (pf) stageB(buf, 1, k2);
      asm volatile("" ::: "memory");
      __builtin_amdgcn_s_barrier();
      asm volatile("s_waitcnt lgkmcnt(0)" ::: "memory");
      MFMA16(4, 2)
      asm volatile("" ::: "memory");
      __builtin_amdgcn_s_barrier();
      // P4: stage A1(s+2) ; MFMA (mi4-7, j0-1) ; counted gate
      if (pf) stageA(buf, 1, k2);
      MFMA16(4, 0)
      if (pf)              asm volatile("s_waitcnt vmcnt(8)" ::: "memory");
      else if (s + 1 < nt) asm volatile("s_waitcnt vmcnt(0)" ::: "memory");
      __builtin_amdgcn_s_barrier();
    } else {
      // P1: ALL reads ; MFMA (mi0-3, j0-1)  [read-before-stage: no region hazard]
      readA(buf, 0); readB(buf, 0); readB(buf, 1);
      asm volatile("" ::: "memory");
      __builtin_amdgcn_s_barrier();
      asm volatile("s_waitcnt lgkmcnt(0)" ::: "memory");
      MFMA16(0, 0)
      asm volatile("" ::: "memory");
      __builtin_amdgcn_s_barrier();
      // P2: stage all(s+2) ; MFMA (mi0-3, j2-3) ; counted gate
      if (pf) { stageA(buf, 0, k2); stageB(buf, 0, k2); stageB(buf, 1, k2); }
      MFMA16(0, 2)
      if (pf)              asm volatile("s_waitcnt vmcnt(6)" ::: "memory");
      else if (s + 1 < nt) asm volatile("s_waitcnt vmcnt(0)" ::: "memory");
      __builtin_amdgcn_s_barrier();
    }
  }

  // ---------------- epilogue ----------------
  const int g = lane >> 4, c15 = lane & 15;
  float bj[4];
#pragma unroll
  for (int j = 0; j < 4; ++j) bj[j] = bias[n0 + wc * 64 + j * 16 + c15];

  if (MODE == 0) {
    float* out = (float*)out0;
#pragma unroll
    for (int mi = 0; mi < MI; ++mi)
#pragma unroll
      for (int j = 0; j < 4; ++j) {
        int gr = m0 + wr * (BM / 2) + mi * 16 + g * 4;
        int gc = n0 + wc * 64 + j * 16 + c15;
#pragma unroll
        for (int r = 0; r < 4; ++r)
          out[(size_t)(gr + r) * N + gc] = acc[mi][j][r] + bj[j];
      }
  } else {
    if (n0 < 768) {            // q block: per-row softmax over this wave's 64 cols (one head)
      unsigned short* qsm = (unsigned short*)out0;
      const int cbase = n0 + wc * 64;
#pragma unroll
      for (int mi = 0; mi < MI; ++mi) {
#pragma unroll
        for (int r = 0; r < 4; ++r) {
          int gr = m0 + wr * (BM / 2) + mi * 16 + g * 4 + r;
          float v[4];
#pragma unroll
          for (int j = 0; j < 4; ++j) v[j] = acc[mi][j][r] + bj[j];
          float mx = fmaxf(fmaxf(v[0], v[1]), fmaxf(v[2], v[3]));
#pragma unroll
          for (int st = 1; st < 16; st <<= 1) mx = fmaxf(mx, __shfl_xor(mx, st));
          float p[4], sm = 0.f;
#pragma unroll
          for (int j = 0; j < 4; ++j) { p[j] = __expf(v[j] - mx); sm += p[j]; }
#pragma unroll
          for (int st = 1; st < 16; st <<= 1) sm += __shfl_xor(sm, st);
          float inv = 1.0f / sm;
#pragma unroll
          for (int j = 0; j < 4; ++j)
            qsm[(size_t)gr * 768 + cbase + j * 16 + c15] = f2bf(p[j] * inv);
        }
      }
    } else {                   // k or v block: fp16 compact store
      _Float16* dst = (n0 < 1536) ? (_Float16*)out1 : (_Float16*)out2;
      const int cbase = (n0 < 1536 ? n0 - 768 : n0 - 1536) + wc * 64;
#pragma unroll
      for (int mi = 0; mi < MI; ++mi)
#pragma unroll
        for (int j = 0; j < 4; ++j) {
          int gr = m0 + wr * (BM / 2) + mi * 16 + g * 4;
          int cc = cbase + j * 16 + c15;
#pragma unroll
          for (int r = 0; r < 4; ++r)
            dst[(size_t)(gr + r) * 768 + cc] = (_Float16)(acc[mi][j][r] + bj[j]);
        }
    }
  }
#undef MFMA16
}

// ---------------- KV partial (NO atomics): kv_part[split][bh][d][e], z_part[split][bh][d] ----------------
__global__ __launch_bounds__(256) void kv_partial(const _Float16* __restrict__ kh,
                                                  const _Float16* __restrict__ vh,
                                                  float* __restrict__ kv_part,
                                                  float* __restrict__ z_part) {
  const int bh = blockIdx.x, b = bh / 12, h = bh % 12;
  const int split = blockIdx.y;
  __shared__ float ek_s[64][68];
  __shared__ float v_s[64][68];
  __shared__ float zred[4][64];
  const int t = threadIdx.x;
  const int d0 = (t >> 4) * 4, e0 = (t & 15) * 4;
  const int zd = t & 63, zq = t >> 6;
  float acc[4][4] = {};
  float zp = 0.f;
  const size_t base = (size_t)b * 4096 * 768 + h * 64;

  for (int nc = 0; nc < 8; ++nc) {
    int n0 = split * 512 + nc * 64;
#pragma unroll
    for (int j = 0; j < 2; ++j) {
      int vi = t + j * 256;
      int row = vi >> 3, c8 = (vi & 7) * 8;
      size_t gp = base + (size_t)(n0 + row) * 768 + c8;
      f16x8 k8 = *(const f16x8*)(kh + gp);
      f16x8 v8 = *(const f16x8*)(vh + gp);
      f32x4 e0v, e1v, v0v, v1v;
#pragma unroll
      for (int u = 0; u < 4; ++u) {
        e0v[u] = __expf((float)k8[u]); e1v[u] = __expf((float)k8[4 + u]);
        v0v[u] = (float)v8[u];         v1v[u] = (float)v8[4 + u];
      }
      *(f32x4*)&ek_s[row][c8] = e0v; *(f32x4*)&ek_s[row][c8 + 4] = e1v;
      *(f32x4*)&v_s[row][c8]  = v0v; *(f32x4*)&v_s[row][c8 + 4]  = v1v;
    }
    __syncthreads();
#pragma unroll 4
    for (int r = 0; r < 16; ++r) zp += ek_s[zq * 16 + r][zd];
#pragma unroll 8
    for (int n = 0; n < 64; ++n) {
      f32x4 ekv = *(const f32x4*)&ek_s[n][d0];
      f32x4 vv  = *(const f32x4*)&v_s[n][e0];
#pragma unroll
      for (int i = 0; i < 4; ++i)
#pragma unroll
        for (int j = 0; j < 4; ++j)
          acc[i][j] += ekv[i] * vv[j];
    }
    __syncthreads();
  }
  // direct stores (private per-split buffers; no contention)
  float* kvp = kv_part + ((size_t)split * 96 + bh) * 4096;
#pragma unroll
  for (int i = 0; i < 4; ++i)
#pragma unroll
    for (int j = 0; j < 4; ++j)
      kvp[(d0 + i) * 64 + e0 + j] = acc[i][j];
  zred[zq][zd] = zp;
  __syncthreads();
  if (t < 64)
    z_part[((size_t)split * 96 + bh) * 64 + t] =
        zred[0][t] + zred[1][t] + zred[2][t] + zred[3][t];
}

// ---------------- Weff: weffT[b][c][h*64+d] = sum_e kv_n[b,h,d,e] * Wp[c][h*64+e] ----------------
__global__ __launch_bounds__(256) void weff_build(const float* __restrict__ kv_part,
                                                  const float* __restrict__ z_part,
                                                  const float* __restrict__ Wp,
                                                  unsigned short* __restrict__ weffT) {
  const int c0 = blockIdx.x * 64, h = blockIdx.y, b = blockIdx.z;
  const int bh = b * 12 + h;
  __shared__ float kvn[64][65];
  __shared__ float zs[64];
  const int t = threadIdx.x;
  if (t < 64) {
    float s = 0.f;
#pragma unroll
    for (int sp = 0; sp < 8; ++sp) s += z_part[((size_t)sp * 96 + bh) * 64 + t];
    zs[t] = s * 8.0f;                       // fold /sqrt(D)
  }
  __syncthreads();
#pragma unroll
  for (int i = 0; i < 16; ++i) {
    int idx = t + i * 256;
    int d = idx >> 6;
    float s = 0.f;
#pragma unroll
    for (int sp = 0; sp < 8; ++sp) s += kv_part[((size_t)sp * 96 + bh) * 4096 + idx];
    kvn[d][idx & 63] = s / zs[d];
  }
  __syncthreads();
  const int c = c0 + (t >> 2);
  const int d0 = (t & 3) * 16;
  const float* wrow = Wp + (size_t)c * 768 + h * 64;
  float acc[16] = {};
#pragma unroll 8
  for (int e = 0; e < 64; ++e) {
    float w = wrow[e];
#pragma unroll
    for (int dd = 0; dd < 16; ++dd) acc[dd] += w * kvn[d0 + dd][e];
  }
  unsigned short* orow = weffT + (size_t)b * 589824 + (size_t)c * 768 + h * 64 + d0;
#pragma unroll
  for (int dd = 0; dd < 16; ++dd) orow[dd] = f2bf(acc[dd]);
}

// ---------------- launch ----------------
extern "C" void kernel_launch(void* const* d_in, const int* in_sizes, int n_in,
                              void* d_out, int out_size, void* d_ws, size_t ws_size,
                              hipStream_t stream) {
  const float* x  = (const float*)d_in[0];
  const float* Wq = (const float*)d_in[1];
  const float* bq = (const float*)d_in[2];
  const float* Wk = (const float*)d_in[3];
  const float* bk = (const float*)d_in[4];
  const float* Wv = (const float*)d_in[5];
  const float* bv = (const float*)d_in[6];
  const float* Wp = (const float*)d_in[7];
  const float* bp = (const float*)d_in[8];

  const size_t MT = 32768;
  const size_t XE = MT * 768;
  const size_t WE = 768 * 768;

  unsigned short* x_bf    = (unsigned short*)d_ws;           // 48 MB
  unsigned short* wqkv_bf = x_bf + XE;                        // 3.4 MB
  unsigned short* q_sm    = wqkv_bf + 3 * WE;                 // 48 MB (bf16 softmaxed q)
  _Float16* k_h = (_Float16*)(q_sm + XE);                     // 48 MB
  _Float16* v_h = k_h + XE;                                   // 48 MB
  unsigned short* weffT = (unsigned short*)(v_h + XE);        // 9.4 MB
  float* bqkv    = (float*)(weffT + 8 * WE);                  // 9 KB
  float* kv_part = bqkv + 2304;                               // 12.6 MB (8 splits)
  float* z_part  = kv_part + (size_t)8 * 96 * 4096;           // 196 KB

  prep<<<2313, 256, 0, stream>>>(x, Wq, Wk, Wv, bq, bk, bv, x_bf, wqkv_bf, bqkv);

  // fused QKV GEMM: [32768,768] x [2304,768]^T ; epilogue q-softmax / k,v fp16
  gemm256<1, 2><<<1152, 512, 0, stream>>>(x_bf, wqkv_bf, bqkv, q_sm, k_h, v_h, 2304, 768, 9, 0);

  kv_partial<<<dim3(96, 8), 256, 0, stream>>>(k_h, v_h, kv_part, z_part);
  weff_build<<<dim3(12, 12, 8), 256, 0, stream>>>(kv_part, z_part, Wp, weffT);

  // out = q_sm @ Weff_b^T + bp  (BM=128: 768 blocks)
  gemm256<0, 1><<<768, 512, 0, stream>>>(q_sm, weffT, bp, d_out, nullptr, nullptr, 768, 768, 3, 1);
}